// Round 5
// baseline (966.649 us; speedup 1.0000x reference)
//
#include <hip/hip_runtime.h>
#include <hip/hip_bf16.h>
#include <math.h>

#define N_NODES 100000
#define N_EDGES 3200000
#define F0 489
#define KPAD 512
#define NB_SCAN 391    // ceil(100000/256)
#define NBUCK 25       // dst>>12, 0..24
#define BSHIFT 12
#define BIN_CHUNK 2048 // edges per block in k_binwrite (256 thr x 8)
#define FILL_SLICES 16

typedef __attribute__((ext_vector_type(8))) short short8;
typedef __attribute__((ext_vector_type(4))) float f32x4;
typedef unsigned short ushort_t;
typedef unsigned int uint_t;
typedef unsigned long long u64;

__device__ __forceinline__ short f2bf(float v) {
    return __builtin_bit_cast(short, __float2bfloat16(v));
}
__device__ __forceinline__ float bf2f(ushort_t u) {
    union { uint_t i; float f; } c;
    c.i = ((uint_t)u) << 16;
    return c.f;
}

// ---------------- zero int buffer ----------------
__global__ void k_zero(int* a, int n) {
    int i = blockIdx.x * blockDim.x + threadIdx.x;
    if (i < n) a[i] = 0;
}

// ---------------- integer degree histogram (dst) ----------------
__global__ void k_count(const int* __restrict__ dst, int* deg) {
    int e = blockIdx.x * blockDim.x + threadIdx.x;
    if (e < N_EDGES) atomicAdd(&deg[dst[e]], 1);
}

// ---------------- bucket histogram (LDS-aggregated) ----------------
__global__ __launch_bounds__(256) void k_bcount(const int* __restrict__ dst,
                                                int* __restrict__ bcnt) {
    __shared__ int lc[32];
    if (threadIdx.x < 32) lc[threadIdx.x] = 0;
    __syncthreads();
    for (int e = blockIdx.x * 256 + threadIdx.x; e < N_EDGES; e += gridDim.x * 256)
        atomicAdd(&lc[dst[e] >> BSHIFT], 1);
    __syncthreads();
    if (threadIdx.x < NBUCK && lc[threadIdx.x] > 0)
        atomicAdd(&bcnt[threadIdx.x], lc[threadIdx.x]);
}

// ---------------- tiny bucket scan ----------------
__global__ void k_bscan(const int* __restrict__ bcnt, int* __restrict__ bbase) {
    if (threadIdx.x == 0) {
        int run = 0;
        for (int i = 0; i < NBUCK; i++) { bbase[i] = run; run += bcnt[i]; }
        bbase[NBUCK] = run;
    }
}

// ---------------- bin edges into bucket-contiguous (src,dst) stream ----------------
__global__ __launch_bounds__(256) void k_binwrite(const int* __restrict__ src,
                                                  const int* __restrict__ dst,
                                                  const int* __restrict__ bbase,
                                                  int* __restrict__ bcur,
                                                  u64* __restrict__ binned) {
    __shared__ int lcnt[32];
    __shared__ int lbase[32];
    if (threadIdx.x < 32) lcnt[threadIdx.x] = 0;
    __syncthreads();
    int e0 = blockIdx.x * BIN_CHUNK;
    u64 sd[8];
    int br[8];
#pragma unroll
    for (int i = 0; i < 8; i++) {
        int e = e0 + i * 256 + threadIdx.x;
        br[i] = -1;
        if (e < N_EDGES) {
            uint_t s = (uint_t)src[e];
            uint_t d = (uint_t)dst[e];
            sd[i] = (u64)s | ((u64)d << 32);
            int b = (int)(d >> BSHIFT);
            int r = atomicAdd(&lcnt[b], 1);
            br[i] = (b << 16) | r;
        }
    }
    __syncthreads();
    if (threadIdx.x < NBUCK) {
        int c = lcnt[threadIdx.x];
        lbase[threadIdx.x] = (c > 0) ? (bbase[threadIdx.x] + atomicAdd(&bcur[threadIdx.x], c)) : 0;
    }
    __syncthreads();
#pragma unroll
    for (int i = 0; i < 8; i++) {
        if (br[i] >= 0) {
            int b = br[i] >> 16;
            int r = br[i] & 0xffff;
            binned[lbase[b] + r] = sd[i];
        }
    }
}

// ---------------- CSR fill from binned buckets (L2-local writes) ----------------
__global__ __launch_bounds__(256) void k_fill2(const int* __restrict__ bbase,
                                               const u64* __restrict__ binned,
                                               const int* __restrict__ rowptr,
                                               int* __restrict__ cur,
                                               int* __restrict__ csr) {
    int b = blockIdx.x / FILL_SLICES;
    int s = blockIdx.x % FILL_SLICES;
    int lo = bbase[b], hi = bbase[b + 1];
    for (int i = lo + s * 256 + threadIdx.x; i < hi; i += FILL_SLICES * 256) {
        u64 p = binned[i];
        int sn = (int)(p & 0xffffffffu);
        int d = (int)(p >> 32);
        int pos = rowptr[d] + atomicAdd(&cur[d], 1);
        csr[pos] = sn;
    }
}

// ---------------- scan ----------------
__global__ __launch_bounds__(256) void k_scan1(const int* __restrict__ deg,
                                               int* __restrict__ rowptr,
                                               int* __restrict__ bsums) {
    __shared__ int tmp[256];
    int i = blockIdx.x * 256 + threadIdx.x;
    int v = (i < N_NODES) ? deg[i] : 0;
    tmp[threadIdx.x] = v;
    __syncthreads();
    for (int off = 1; off < 256; off <<= 1) {
        int t = (threadIdx.x >= off) ? tmp[threadIdx.x - off] : 0;
        __syncthreads();
        tmp[threadIdx.x] += t;
        __syncthreads();
    }
    if (i < N_NODES) rowptr[i] = tmp[threadIdx.x];
    if (threadIdx.x == 255) bsums[blockIdx.x] = tmp[255];
}

__global__ __launch_bounds__(512) void k_scan2(const int* __restrict__ bsums,
                                               int* __restrict__ boffs) {
    __shared__ int tmp[512];
    int i = threadIdx.x;
    int v = (i < NB_SCAN) ? bsums[i] : 0;
    tmp[i] = v;
    __syncthreads();
    for (int off = 1; off < 512; off <<= 1) {
        int t = (i >= off) ? tmp[i - off] : 0;
        __syncthreads();
        tmp[i] += t;
        __syncthreads();
    }
    if (i < NB_SCAN) boffs[i] = tmp[i] - v;
}

// also computes dinv = rsqrt(deg+1)
__global__ __launch_bounds__(256) void k_scan3(int* __restrict__ rowptr,
                                               const int* __restrict__ deg,
                                               const int* __restrict__ boffs,
                                               float* __restrict__ dinv) {
    int i = blockIdx.x * 256 + threadIdx.x;
    if (i < N_NODES) {
        int d = deg[i];
        rowptr[i] = rowptr[i] - d + boffs[blockIdx.x];
        dinv[i] = rsqrtf((float)d + 1.0f);
    }
    if (i == 0) rowptr[N_NODES] = N_EDGES;
}

// ---------------- W1 -> bf16, transposed+padded: Wt[n][k], n<64, k<512 ----------------
__global__ void k_cvtW(const float* __restrict__ W1, short* __restrict__ Wt) {
    int i = blockIdx.x * 256 + threadIdx.x;
    if (i < 64 * KPAD) {
        int n = i >> 9, k = i & (KPAD - 1);
        float v = (k < F0) ? W1[k * 64 + n] : 0.f;
        Wt[i] = f2bf(v);
    }
}

// ---------------- layer 1 MFMA GEMM: g1 = bf16( dinv .* (x @ W1) ) ----------------
__global__ __launch_bounds__(256) void k_gemm1_mfma(const float* __restrict__ x,
                                                    const short* __restrict__ Wt,
                                                    const float* __restrict__ dinv,
                                                    ushort_t* __restrict__ g1) {
    int wave = threadIdx.x >> 6;
    int lane = threadIdx.x & 63;
    int quad = lane >> 4;
    int m = lane & 15;
    int row0 = blockIdx.x * 64 + wave * 16;
    int row = row0 + m;
    int rowc = row < N_NODES ? row : N_NODES - 1;
    const float* xr = x + (size_t)rowc * F0;

    f32x4 acc0 = {0.f, 0.f, 0.f, 0.f};
    f32x4 acc1 = {0.f, 0.f, 0.f, 0.f};
    f32x4 acc2 = {0.f, 0.f, 0.f, 0.f};
    f32x4 acc3 = {0.f, 0.f, 0.f, 0.f};

    const short* wb = Wt + m * KPAD + quad * 8;

    // ks = 0..14: all lanes in-bounds (kb+8 <= 480+8 <= 489) -> branch-free
    for (int ks = 0; ks < 15; ks++) {
        int kb = ks * 32 + quad * 8;
        short8 af;
#pragma unroll
        for (int j = 0; j < 8; j++) af[j] = f2bf(xr[kb + j]);
        const short* wk = wb + ks * 32;
        short8 b0 = *(const short8*)(wk);
        short8 b1 = *(const short8*)(wk + 16 * KPAD);
        short8 b2 = *(const short8*)(wk + 32 * KPAD);
        short8 b3 = *(const short8*)(wk + 48 * KPAD);
        acc0 = __builtin_amdgcn_mfma_f32_16x16x32_bf16(af, b0, acc0, 0, 0, 0);
        acc1 = __builtin_amdgcn_mfma_f32_16x16x32_bf16(af, b1, acc1, 0, 0, 0);
        acc2 = __builtin_amdgcn_mfma_f32_16x16x32_bf16(af, b2, acc2, 0, 0, 0);
        acc3 = __builtin_amdgcn_mfma_f32_16x16x32_bf16(af, b3, acc3, 0, 0, 0);
    }
    // ks = 15 tail: guard per element
    {
        int kb = 480 + quad * 8;
        short8 af;
#pragma unroll
        for (int j = 0; j < 8; j++) af[j] = (kb + j < F0) ? f2bf(xr[kb + j]) : (short)0;
        const short* wk = wb + 15 * 32;
        short8 b0 = *(const short8*)(wk);
        short8 b1 = *(const short8*)(wk + 16 * KPAD);
        short8 b2 = *(const short8*)(wk + 32 * KPAD);
        short8 b3 = *(const short8*)(wk + 48 * KPAD);
        acc0 = __builtin_amdgcn_mfma_f32_16x16x32_bf16(af, b0, acc0, 0, 0, 0);
        acc1 = __builtin_amdgcn_mfma_f32_16x16x32_bf16(af, b1, acc1, 0, 0, 0);
        acc2 = __builtin_amdgcn_mfma_f32_16x16x32_bf16(af, b2, acc2, 0, 0, 0);
        acc3 = __builtin_amdgcn_mfma_f32_16x16x32_bf16(af, b3, acc3, 0, 0, 0);
    }

    // D layout: col = lane&15, row = quad*4 + reg
#pragma unroll
    for (int r = 0; r < 4; r++) {
        int orow = row0 + quad * 4 + r;
        if (orow < N_NODES) {
            float s = dinv[orow];
            ushort_t* gr = g1 + (size_t)orow * 64 + m;
            gr[0]  = (ushort_t)f2bf(s * acc0[r]);
            gr[16] = (ushort_t)f2bf(s * acc1[r]);
            gr[32] = (ushort_t)f2bf(s * acc2[r]);
            gr[48] = (ushort_t)f2bf(s * acc3[r]);
        }
    }
}

// ---------------- gather, 64 bf16 features -> fp32 agg ----------------
__global__ __launch_bounds__(256) void k_gather64(const int* __restrict__ rowptr,
                                                  const int* __restrict__ csr,
                                                  const ushort_t* __restrict__ g,
                                                  float* __restrict__ agg) {
    int node = blockIdx.x * 4 + (threadIdx.x >> 6);
    int f = threadIdx.x & 63;
    int beg = rowptr[node], end = rowptr[node + 1];
    float acc = bf2f(g[(size_t)node * 64 + f]);  // self loop
    for (int j0 = beg; j0 < end; j0 += 64) {
        int n = end - j0;
        if (n > 64) n = 64;
        int e = csr[j0 + (f < n ? f : 0)];
        float a0 = 0.f, a1 = 0.f;
        int i = 0;
        for (; i + 2 <= n; i += 2) {
            int s0 = __shfl(e, i, 64);
            int s1 = __shfl(e, i + 1, 64);
            a0 += bf2f(g[(size_t)s0 * 64 + f]);
            a1 += bf2f(g[(size_t)s1 * 64 + f]);
        }
        if (i < n) {
            int s0 = __shfl(e, i, 64);
            a0 += bf2f(g[(size_t)s0 * 64 + f]);
        }
        acc += a0 + a1;
    }
    agg[(size_t)node * 64 + f] = acc;
}

// ---------------- gather, 32 bf16 features -> fp32 agg ----------------
__global__ __launch_bounds__(256) void k_gather32(const int* __restrict__ rowptr,
                                                  const int* __restrict__ csr,
                                                  const ushort_t* __restrict__ g,
                                                  float* __restrict__ agg) {
    int t = blockIdx.x * 256 + threadIdx.x;
    int node = t >> 5;
    int f = t & 31;
    int beg = rowptr[node], end = rowptr[node + 1];
    float acc = bf2f(g[(size_t)node * 32 + f]);
    for (int j0 = beg; j0 < end; j0 += 32) {
        int n = end - j0;
        if (n > 32) n = 32;
        int e = csr[j0 + (f < n ? f : 0)];
        float a0 = 0.f, a1 = 0.f;
        int i = 0;
        for (; i + 2 <= n; i += 2) {
            int s0 = __shfl(e, i, 32);
            int s1 = __shfl(e, i + 1, 32);
            a0 += bf2f(g[(size_t)s0 * 32 + f]);
            a1 += bf2f(g[(size_t)s1 * 32 + f]);
        }
        if (i < n) {
            int s0 = __shfl(e, i, 32);
            a0 += bf2f(g[(size_t)s0 * 32 + f]);
        }
        acc += a0 + a1;
    }
    agg[(size_t)node * 32 + f] = acc;
}

// ---------------- gather, 2 fp32 features ----------------
__global__ __launch_bounds__(256) void k_gather2(const int* __restrict__ rowptr,
                                                 const int* __restrict__ csr,
                                                 const float* __restrict__ g,
                                                 float* __restrict__ agg) {
    int t = blockIdx.x * 256 + threadIdx.x;
    if (t >= N_NODES * 2) return;
    int node = t >> 1;
    int f = t & 1;
    int beg = rowptr[node], end = rowptr[node + 1];
    float acc = g[(size_t)node * 2 + f];
    for (int j = beg; j < end; j++) {
        int s = csr[j];
        acc += g[(size_t)s * 2 + f];
    }
    agg[(size_t)node * 2 + f] = acc;
}

// ---------------- layer 2: g2 = bf16( dinv .* (relu(dinv*agg1+b1) @ W2) ) ----------------
__global__ __launch_bounds__(256) void k_layer2(const float* __restrict__ agg1,
                                                const float* __restrict__ dinv,
                                                const float* __restrict__ b1,
                                                const float* __restrict__ W2,
                                                ushort_t* __restrict__ g2) {
    __shared__ float hs[32][65];
    __shared__ float Ws[64 * 32];
    for (int i = threadIdx.x; i < 64 * 32; i += 256) Ws[i] = W2[i];
    int row0 = blockIdx.x * 32;
    for (int i = threadIdx.x; i < 32 * 64; i += 256) {
        int r = i >> 6, f = i & 63;
        int row = row0 + r;
        float v = dinv[row] * agg1[(size_t)row * 64 + f] + b1[f];
        hs[r][f] = fmaxf(v, 0.f);
    }
    __syncthreads();
    int r = threadIdx.x >> 3;
    int j0 = (threadIdx.x & 7) * 4;
    int row = row0 + r;
    float a0 = 0.f, a1 = 0.f, a2 = 0.f, a3 = 0.f;
#pragma unroll 8
    for (int f = 0; f < 64; f++) {
        float h = hs[r][f];
        a0 += h * Ws[f * 32 + j0 + 0];
        a1 += h * Ws[f * 32 + j0 + 1];
        a2 += h * Ws[f * 32 + j0 + 2];
        a3 += h * Ws[f * 32 + j0 + 3];
    }
    float s = dinv[row];
    ushort_t* gr = g2 + (size_t)row * 32 + j0;
    gr[0] = (ushort_t)f2bf(s * a0);
    gr[1] = (ushort_t)f2bf(s * a1);
    gr[2] = (ushort_t)f2bf(s * a2);
    gr[3] = (ushort_t)f2bf(s * a3);
}

// ---------------- layer 3 ----------------
__global__ __launch_bounds__(256) void k_layer3(const float* __restrict__ agg2,
                                                const float* __restrict__ dinv,
                                                const float* __restrict__ b2,
                                                const float* __restrict__ W3,
                                                float* __restrict__ g3) {
    int row = blockIdx.x * blockDim.x + threadIdx.x;
    if (row >= N_NODES) return;
    float s = dinv[row];
    float t0 = 0.f, t1 = 0.f;
    const float4* ar = reinterpret_cast<const float4*>(agg2 + (size_t)row * 32);
#pragma unroll
    for (int q = 0; q < 8; q++) {
        float4 v = ar[q];
        float h;
        int f = q * 4;
        h = fmaxf(s * v.x + b2[f + 0], 0.f); t0 += h * W3[(f + 0) * 2]; t1 += h * W3[(f + 0) * 2 + 1];
        h = fmaxf(s * v.y + b2[f + 1], 0.f); t0 += h * W3[(f + 1) * 2]; t1 += h * W3[(f + 1) * 2 + 1];
        h = fmaxf(s * v.z + b2[f + 2], 0.f); t0 += h * W3[(f + 2) * 2]; t1 += h * W3[(f + 2) * 2 + 1];
        h = fmaxf(s * v.w + b2[f + 3], 0.f); t0 += h * W3[(f + 3) * 2]; t1 += h * W3[(f + 3) * 2 + 1];
    }
    g3[(size_t)row * 2 + 0] = s * t0;
    g3[(size_t)row * 2 + 1] = s * t1;
}

// ---------------- final log_softmax ----------------
__global__ void k_final(const float* __restrict__ agg3,
                        const float* __restrict__ dinv,
                        const float* __restrict__ b3,
                        float* __restrict__ out) {
    int row = blockIdx.x * blockDim.x + threadIdx.x;
    if (row >= N_NODES) return;
    float s = dinv[row];
    float z0 = s * agg3[(size_t)row * 2 + 0] + b3[0];
    float z1 = s * agg3[(size_t)row * 2 + 1] + b3[1];
    float m = fmaxf(z0, z1);
    float lse = m + logf(expf(z0 - m) + expf(z1 - m));
    out[(size_t)row * 2 + 0] = z0 - lse;
    out[(size_t)row * 2 + 1] = z1 - lse;
}

extern "C" void kernel_launch(void* const* d_in, const int* in_sizes, int n_in,
                              void* d_out, int out_size, void* d_ws, size_t ws_size,
                              hipStream_t stream) {
    const float* x  = (const float*)d_in[0];
    const int*   ei = (const int*)d_in[1];
    const float* W1 = (const float*)d_in[2];
    const float* b1 = (const float*)d_in[3];
    const float* W2 = (const float*)d_in[4];
    const float* b2 = (const float*)d_in[5];
    const float* W3 = (const float*)d_in[6];
    const float* b3 = (const float*)d_in[7];
    float* out = (float*)d_out;

    const int* src = ei;
    const int* dst = ei + N_EDGES;

    // ---- workspace layout (int elements) ----
    int* deg_i  = (int*)d_ws;                    // 100000
    int* cur    = deg_i + 100000;                // 100000
    int* bcnt   = cur + 100000;                  // 32
    int* bcur   = bcnt + 32;                     // 32   (zeroed with deg/cur/bcnt)
    int* bsums  = bcur + 32;                     // 512
    int* boffs  = bsums + 512;                   // 512
    int* bbase  = boffs + 512;                   // 36
    int* rowptr = bbase + 36;                    // 100004
    int* csr    = rowptr + 100004;               // 3200000
    float* dinv = (float*)(csr + 3200000);       // 100000
    short* Wt   = (short*)(dinv + 100000);       // 32768 shorts = 16384 ints
    ushort_t* gbuf = (ushort_t*)((int*)Wt + 16384);       // N*64 ushorts = 12.8 MB
    float* aggF = (float*)(gbuf + (size_t)N_NODES * 64);  // N*64 fp32 = 25.6 MB
    u64* binned = (u64*)gbuf;                    // 25.6 MB, aliases gbuf+aggF head (dead before gemm1)

    ushort_t* gb1 = gbuf;
    ushort_t* gb2 = gbuf;
    float* g3     = (float*)gbuf;
    float* agg1 = aggF;
    float* agg2 = aggF;
    float* agg3 = aggF;

    const int TB = 256;
    int nb_nodes = (N_NODES + TB - 1) / TB;      // 391
    int nb_edges = (N_EDGES + TB - 1) / TB;      // 12500
    int nb_bin   = (N_EDGES + BIN_CHUNK - 1) / BIN_CHUNK;  // 1563

    k_zero<<<(200064 + TB - 1) / TB, TB, 0, stream>>>(deg_i, 200064);  // deg+cur+bcnt+bcur
    k_count<<<nb_edges, TB, 0, stream>>>(dst, deg_i);
    k_bcount<<<2048, TB, 0, stream>>>(dst, bcnt);
    k_scan1<<<NB_SCAN, 256, 0, stream>>>(deg_i, rowptr, bsums);
    k_scan2<<<1, 512, 0, stream>>>(bsums, boffs);
    k_scan3<<<NB_SCAN, 256, 0, stream>>>(rowptr, deg_i, boffs, dinv);
    k_bscan<<<1, 64, 0, stream>>>(bcnt, bbase);
    k_binwrite<<<nb_bin, TB, 0, stream>>>(src, dst, bbase, bcur, binned);
    k_fill2<<<NBUCK * FILL_SLICES, TB, 0, stream>>>(bbase, binned, rowptr, cur, csr);
    k_cvtW<<<(64 * KPAD + 255) / 256, 256, 0, stream>>>(W1, Wt);

    k_gemm1_mfma<<<(N_NODES + 63) / 64, TB, 0, stream>>>(x, Wt, dinv, gb1);
    k_gather64<<<N_NODES / 4, TB, 0, stream>>>(rowptr, csr, gb1, agg1);

    k_layer2<<<N_NODES / 32, TB, 0, stream>>>(agg1, dinv, b1, W2, gb2);
    k_gather32<<<N_NODES / 8, TB, 0, stream>>>(rowptr, csr, gb2, agg2);

    k_layer3<<<nb_nodes, TB, 0, stream>>>(agg2, dinv, b2, W3, g3);
    k_gather2<<<(2 * N_NODES + TB - 1) / TB, TB, 0, stream>>>(rowptr, csr, g3, agg3);

    k_final<<<nb_nodes, TB, 0, stream>>>(agg3, dinv, b3, out);
}